// Round 6
// baseline (3286.972 us; speedup 1.0000x reference)
//
#include <hip/hip_runtime.h>

#define NB    32
#define SEQ   128
#define WCH   20
#define CED   50
#define NFLT  64
#define WDIM  300
#define HD    512
#define NWORD 4096
#define LPAD  11
#define NEGV  -10000.0f
#define LSTM_BLOCKS 16

typedef float f32x4 __attribute__((ext_vector_type(4)));
typedef float f32x16 __attribute__((ext_vector_type(16)));
typedef __bf16 bf16x8 __attribute__((ext_vector_type(8)));
typedef unsigned short u16x8 __attribute__((ext_vector_type(8)));
typedef unsigned short u16x4 __attribute__((ext_vector_type(4)));
typedef unsigned long long ull;
typedef unsigned long long ullx2 __attribute__((ext_vector_type(2)));

static __device__ __forceinline__ unsigned short f2bf(float f) {
  unsigned u = __builtin_bit_cast(unsigned, f);
  u += 0x7fffu + ((u >> 16) & 1u);
  return (unsigned short)(u >> 16);
}
static __device__ __forceinline__ float bf2f(unsigned short s) {
  unsigned u = ((unsigned)s) << 16;
  return __builtin_bit_cast(float, u);
}
static __device__ __forceinline__ float sigf(float x) { return 1.0f / (1.0f + expf(-x)); }

// ---------------------------------------------------------------- char CNN
__global__ __launch_bounds__(256) void conv_kernel(
    const int* __restrict__ char_ids, const float* __restrict__ char_embed,
    const float* __restrict__ w2, const float* __restrict__ b2,
    const float* __restrict__ w3, const float* __restrict__ b3,
    const float* __restrict__ w4, const float* __restrict__ b4,
    const float* __restrict__ w5, const float* __restrict__ b5,
    float* __restrict__ ch)
{
  __shared__ __align__(16) float xT[CED][WCH];
  int wi = blockIdx.x;
  int tid = threadIdx.x;
  for (int e = tid; e < WCH * CED; e += 256) {
    int p = e / CED, c = e - p * CED;
    int cid = char_ids[wi * WCH + p];
    xT[c][p] = char_embed[cid * CED + c];
  }
  __syncthreads();
  int w = tid >> 6, f = tid & 63;
  int k = w + 2;
  int P = WCH - k + 1;
  const float* cw = (w == 0) ? w2 : (w == 1) ? w3 : (w == 2) ? w4 : w5;
  const float* cb = (w == 0) ? b2 : (w == 1) ? b3 : (w == 2) ? b4 : b5;
  float acc[19];
  #pragma unroll
  for (int p = 0; p < 19; p++) acc[p] = 0.f;
  for (int c = 0; c < CED; c++) {
    float xr[20];
    const float4* rowp = (const float4*)&xT[c][0];
    #pragma unroll
    for (int q = 0; q < 5; q++) {
      float4 v = rowp[q];
      xr[4*q+0] = v.x; xr[4*q+1] = v.y; xr[4*q+2] = v.z; xr[4*q+3] = v.w;
    }
    #pragma unroll
    for (int dw = 0; dw < 5; dw++) {
      if (dw < k) {
        float wv = cw[(dw * CED + c) * NFLT + f];
        #pragma unroll
        for (int p = 0; p < 19; p++) {
          if (p < P) acc[p] += xr[p + dw] * wv;
        }
      }
    }
  }
  float m = acc[0];
  #pragma unroll
  for (int p = 1; p < 19; p++) if (p < P) m = fmaxf(m, acc[p]);
  ch[wi * 256 + w * 64 + f] = fmaxf(0.f, m + cb[f]);
}

// ---------------------------------------------------------------- word gather
__global__ void gather_word_kernel(const int* __restrict__ token_ids,
                                   const float* __restrict__ word_embed,
                                   float* __restrict__ word_in)
{
  int idx = blockIdx.x * 256 + threadIdx.x;
  if (idx < NWORD * WDIM) {
    int i = idx / WDIM, c = idx - i * WDIM;
    word_in[idx] = word_embed[token_ids[i] * WDIM + c];
  }
}

// ---------------------------------------------------------------- generic MFMA GEMM: C = act(A @ B^T + Cin + bias)
__global__ __launch_bounds__(256) void gemm_bt_kernel(
    const float* __restrict__ A, const float* __restrict__ Bw,
    const float* __restrict__ bias, const float* __restrict__ Cin,
    float* __restrict__ Cout, unsigned short* __restrict__ Cbf,
    int M, int N, int K, int act, int gridN)
{
  __shared__ __align__(16) unsigned short As[128 * 32];
  __shared__ __align__(16) unsigned short Bs[128 * 32];
  int bid = blockIdx.x;
  int tm = bid / gridN, tn = bid - tm * gridN;
  int m0 = tm * 128, n0 = tn * 128;
  int tid = threadIdx.x;
  int lane = tid & 63, w = tid >> 6;
  int wr = (w >> 1) * 64, wc = (w & 1) * 64;
  f32x4 acc[4][4] = {};
  int fr = lane & 15, fk = (lane >> 4) * 8;

  for (int k0 = 0; k0 < K; k0 += 32) {
    __syncthreads();
    #pragma unroll
    for (int i = 0; i < 4; i++) {
      int idx = tid + i * 256;
      int r = idx >> 3, c4 = idx & 7;
      int kx = k0 + c4 * 4;
      int ra = m0 + r, rb = n0 + r;
      f32x4 av = {0.f,0.f,0.f,0.f}, bv = {0.f,0.f,0.f,0.f};
      if (kx < K) {
        if (ra < M) av = *(const f32x4*)&A[(size_t)ra * K + kx];
        if (rb < N) bv = *(const f32x4*)&Bw[(size_t)rb * K + kx];
      }
      u16x4 ap, bp;
      #pragma unroll
      for (int j = 0; j < 4; j++) { ap[j] = f2bf(av[j]); bp[j] = f2bf(bv[j]); }
      *(u16x4*)&As[r * 32 + c4 * 4] = ap;
      *(u16x4*)&Bs[r * 32 + c4 * 4] = bp;
    }
    __syncthreads();
    bf16x8 a[4], b[4];
    #pragma unroll
    for (int mt = 0; mt < 4; mt++)
      a[mt] = *(const bf16x8*)&As[(wr + mt * 16 + fr) * 32 + fk];
    #pragma unroll
    for (int nt = 0; nt < 4; nt++)
      b[nt] = *(const bf16x8*)&Bs[(wc + nt * 16 + fr) * 32 + fk];
    #pragma unroll
    for (int mt = 0; mt < 4; mt++)
      #pragma unroll
      for (int nt = 0; nt < 4; nt++)
        acc[mt][nt] = __builtin_amdgcn_mfma_f32_16x16x32_bf16(a[mt], b[nt], acc[mt][nt], 0, 0, 0);
  }

  #pragma unroll
  for (int mt = 0; mt < 4; mt++) {
    #pragma unroll
    for (int nt = 0; nt < 4; nt++) {
      #pragma unroll
      for (int j = 0; j < 4; j++) {
        int row = m0 + wr + mt * 16 + (lane >> 4) * 4 + j;
        int col = n0 + wc + nt * 16 + (lane & 15);
        if (row < M && col < N) {
          float v = acc[mt][nt][j];
          if (Cin)  v += Cin[(size_t)row * N + col];
          if (bias) v += bias[col];
          if (act == 1)      v = tanhf(v);
          else if (act == 2) v = sigf(v);
          if (Cbf) Cbf[(size_t)row * N + col] = f2bf(v);
          else     Cout[(size_t)row * N + col] = v;
        }
      }
    }
  }
}

// ---------------------------------------------------------------- gate combine (+ flag reset)
__global__ void feats_kernel(const float* __restrict__ g, const float* __restrict__ word_in,
                             const float* __restrict__ char_in, float* __restrict__ feats,
                             unsigned* __restrict__ flags)
{
  if (blockIdx.x == 0)
    __hip_atomic_store(&flags[threadIdx.x], 0u, __ATOMIC_RELAXED, __HIP_MEMORY_SCOPE_AGENT);
  int idx = blockIdx.x * 256 + threadIdx.x;
  if (idx < NWORD * WDIM) {
    float gg = g[idx];
    feats[idx] = gg * word_in[idx] + (1.f - gg) * char_in[idx];
  }
}

// ---------------------------------------------------------------- bidirectional LSTM
// 16 blocks x 512 thr; block owns units [sl*32,+32) of BOTH dirs, phases alternate F,B.
// A-fragments register-staged (no LDS h), per-WAVE flags (128/dir), write-once hist.
// hist: [dir][s][batch][unit] bf16. Flags monotonic; reset by feats_kernel.
__global__ __launch_bounds__(512) void lstm_kernel(
    const unsigned short* __restrict__ xg_f, const unsigned short* __restrict__ xg_b,
    const float* __restrict__ whh_f, const float* __restrict__ whh_b,
    const int* __restrict__ lens,
    unsigned short* __restrict__ hist, unsigned* __restrict__ flags)
{
  int sl = blockIdx.x;
  int hs0 = sl << 5;
  int tid = threadIdx.x, lane = tid & 63, w = tid >> 6;
  int g = w & 3, kh = w >> 2;
  int l31 = lane & 31, le = lane >> 5;

  unsigned short* histF = hist;
  unsigned short* histB = hist + (size_t)SEQ * NB * HD;
  unsigned* flF = flags;
  unsigned* flB = flags + 128;
  int myflag = sl * 8 + w;

  // B-fragments: whh row (unit) = g*HD + hs0 + l31 ; k = kh*256 + q*16 + le*8 + j
  bf16x8 wfF[16], wfB[16];
  {
    const float* sF = whh_f + (size_t)(g * HD + hs0 + l31) * HD + kh * 256 + le * 8;
    const float* sB = whh_b + (size_t)(g * HD + hs0 + l31) * HD + kh * 256 + le * 8;
    #pragma unroll
    for (int q = 0; q < 16; q++) {
      u16x8 tf_, tb_;
      #pragma unroll
      for (int j = 0; j < 8; j++) { tf_[j] = f2bf(sF[q * 16 + j]); tb_[j] = f2bf(sB[q * 16 + j]); }
      wfF[q] = __builtin_bit_cast(bf16x8, tf_);
      wfB[q] = __builtin_bit_cast(bf16x8, tb_);
    }
  }

  __shared__ float Gs[2][2][NB][132];     // [dir][kh][batch][g*32+col]

  int b = tid >> 4, up = tid & 15;
  int mylen = lens[b];
  float cF[2] = {0.f,0.f}, hpF[2] = {0.f,0.f};
  float cB[2] = {0.f,0.f}, hpB[2] = {0.f,0.f};
  ull af[32];                              // A-frag buffer, alternates F/B

  auto pollflags = [&](unsigned* fl, unsigned tgt) {
    const ull* fp = (const ull*)fl;
    for (;;) {
      ull v = __hip_atomic_load(fp + lane, __ATOMIC_RELAXED, __HIP_MEMORY_SCOPE_AGENT);
      bool ok = ((unsigned)v >= tgt) && ((unsigned)(v >> 32) >= tgt);
      if (__all(ok)) break;
      __builtin_amdgcn_s_sleep(1);
    }
  };

  // xg preload for s=0
  unsigned xF[4], xB[4];
  {
    const unsigned* pF = (const unsigned*)xg_f;
    const unsigned* pB = (const unsigned*)xg_b;
    size_t oF = (size_t)(b * SEQ + 0) * 1024 + (hs0 >> 1) + up;
    size_t oB = (size_t)(b * SEQ + (SEQ - 1)) * 1024 + (hs0 >> 1) + up;
    #pragma unroll
    for (int g4 = 0; g4 < 4; g4++) { xF[g4] = pF[oF + g4 * 256]; xB[g4] = pB[oB + g4 * 256]; }
  }

  for (int s = 0; s < SEQ; s++) {
    // ================= F(s): consume af=hist_f[s-1]; refill af<-hist_b[s-1] =================
    {
      f32x16 acc = {};
      if (s > 0) {
        #pragma unroll
        for (int q = 0; q < 16; q++) {
          ullx2 t2 = { af[2*q], af[2*q+1] };
          acc = __builtin_amdgcn_mfma_f32_32x32x16_bf16(__builtin_bit_cast(bf16x8, t2), wfF[q], acc, 0, 0, 0);
        }
      }
      #pragma unroll
      for (int r = 0; r < 16; r++) {
        int row = (r & 3) + 8 * (r >> 2) + 4 * le;
        Gs[0][kh][row][g * 32 + l31] = acc[r];
      }
      if (s > 0) {                                   // detect bwd step s, load hist_b[s-1]
        pollflags(flB, (unsigned)s);
        const ull* base = (const ull*)histB + ((((size_t)(s - 1) * NB + l31) * HD + kh * 256 + le * 8) >> 2);
        #pragma unroll
        for (int q = 0; q < 16; q++) {
          af[2*q]   = __hip_atomic_load(base + q * 4,     __ATOMIC_RELAXED, __HIP_MEMORY_SCOPE_AGENT);
          af[2*q+1] = __hip_atomic_load(base + q * 4 + 1, __ATOMIC_RELAXED, __HIP_MEMORY_SCOPE_AGENT);
        }
      }
      unsigned xn0 = 0, xn1 = 0, xn2 = 0, xn3 = 0;   // xg prefetch F(s+1)
      if (s + 1 < SEQ) {
        const unsigned* pF = (const unsigned*)xg_f;
        size_t o = (size_t)(b * SEQ + (s + 1)) * 1024 + (hs0 >> 1) + up;
        xn0 = pF[o]; xn1 = pF[o + 256]; xn2 = pF[o + 512]; xn3 = pF[o + 768];
      }
      __syncthreads();
      bool mk = (s < mylen);
      float pre[4][2];
      #pragma unroll
      for (int g4 = 0; g4 < 4; g4++) {
        float2 p0 = *(const float2*)&Gs[0][0][b][g4 * 32 + 2 * up];
        float2 p1 = *(const float2*)&Gs[0][1][b][g4 * 32 + 2 * up];
        pre[g4][0] = p0.x + p1.x; pre[g4][1] = p0.y + p1.y;
      }
      unsigned pk = 0;
      #pragma unroll
      for (int j = 0; j < 2; j++) {
        float xi = bf2f((unsigned short)(xF[0] >> (16*j)));
        float xf = bf2f((unsigned short)(xF[1] >> (16*j)));
        float xG = bf2f((unsigned short)(xF[2] >> (16*j)));
        float xo = bf2f((unsigned short)(xF[3] >> (16*j)));
        float iv = sigf(xi + pre[0][j]);
        float fv = sigf(xf + pre[1][j]);
        float Gv = tanhf(xG + pre[2][j]);
        float o_ = sigf(xo + pre[3][j]);
        float cn = fv * cF[j] + iv * Gv;
        float hh = o_ * tanhf(cn);
        if (mk) cF[j] = cn;
        float hk = mk ? hh : hpF[j];
        hpF[j] = hk;
        pk |= ((unsigned)f2bf(hk)) << (16*j);
      }
      unsigned* hd = (unsigned*)histF;
      __hip_atomic_store(&hd[(((size_t)s * NB + b) * HD + hs0 + 2 * up) >> 1], pk,
                         __ATOMIC_RELAXED, __HIP_MEMORY_SCOPE_AGENT);
      xF[0] = xn0; xF[1] = xn1; xF[2] = xn2; xF[3] = xn3;
      asm volatile("s_waitcnt vmcnt(0)" ::: "memory");
      if (lane == 0)
        __hip_atomic_store(&flF[myflag], (unsigned)(s + 1), __ATOMIC_RELAXED, __HIP_MEMORY_SCOPE_AGENT);
    }
    // ================= B(s): consume af=hist_b[s-1]; refill af<-hist_f[s] =================
    {
      int tb = SEQ - 1 - s;
      f32x16 acc = {};
      if (s > 0) {
        #pragma unroll
        for (int q = 0; q < 16; q++) {
          ullx2 t2 = { af[2*q], af[2*q+1] };
          acc = __builtin_amdgcn_mfma_f32_32x32x16_bf16(__builtin_bit_cast(bf16x8, t2), wfB[q], acc, 0, 0, 0);
        }
      }
      #pragma unroll
      for (int r = 0; r < 16; r++) {
        int row = (r & 3) + 8 * (r >> 2) + 4 * le;
        Gs[1][kh][row][g * 32 + l31] = acc[r];
      }
      if (s + 1 < SEQ) {                             // detect fwd step s+1, load hist_f[s]
        pollflags(flF, (unsigned)(s + 1));
        const ull* base = (const ull*)histF + ((((size_t)s * NB + l31) * HD + kh * 256 + le * 8) >> 2);
        #pragma unroll
        for (int q = 0; q < 16; q++) {
          af[2*q]   = __hip_atomic_load(base + q * 4,     __ATOMIC_RELAXED, __HIP_MEMORY_SCOPE_AGENT);
          af[2*q+1] = __hip_atomic_load(base + q * 4 + 1, __ATOMIC_RELAXED, __HIP_MEMORY_SCOPE_AGENT);
        }
      }
      unsigned xn0 = 0, xn1 = 0, xn2 = 0, xn3 = 0;   // xg prefetch B(s+1)
      if (s + 1 < SEQ) {
        const unsigned* pB = (const unsigned*)xg_b;
        size_t o = (size_t)(b * SEQ + (SEQ - 2 - s)) * 1024 + (hs0 >> 1) + up;
        xn0 = pB[o]; xn1 = pB[o + 256]; xn2 = pB[o + 512]; xn3 = pB[o + 768];
      }
      __syncthreads();
      bool mk = (tb < mylen);
      float pre[4][2];
      #pragma unroll
      for (int g4 = 0; g4 < 4; g4++) {
        float2 p0 = *(const float2*)&Gs[1][0][b][g4 * 32 + 2 * up];
        float2 p1 = *(const float2*)&Gs[1][1][b][g4 * 32 + 2 * up];
        pre[g4][0] = p0.x + p1.x; pre[g4][1] = p0.y + p1.y;
      }
      unsigned pk = 0;
      #pragma unroll
      for (int j = 0; j < 2; j++) {
        float xi = bf2f((unsigned short)(xB[0] >> (16*j)));
        float xf = bf2f((unsigned short)(xB[1] >> (16*j)));
        float xG = bf2f((unsigned short)(xB[2] >> (16*j)));
        float xo = bf2f((unsigned short)(xB[3] >> (16*j)));
        float iv = sigf(xi + pre[0][j]);
        float fv = sigf(xf + pre[1][j]);
        float Gv = tanhf(xG + pre[2][j]);
        float o_ = sigf(xo + pre[3][j]);
        float cn = fv * cB[j] + iv * Gv;
        float hh = o_ * tanhf(cn);
        if (mk) cB[j] = cn;
        float hk = mk ? hh : hpB[j];
        hpB[j] = hk;
        pk |= ((unsigned)f2bf(hk)) << (16*j);
      }
      unsigned* hd = (unsigned*)histB;
      __hip_atomic_store(&hd[(((size_t)s * NB + b) * HD + hs0 + 2 * up) >> 1], pk,
                         __ATOMIC_RELAXED, __HIP_MEMORY_SCOPE_AGENT);
      xB[0] = xn0; xB[1] = xn1; xB[2] = xn2; xB[3] = xn3;
      asm volatile("s_waitcnt vmcnt(0)" ::: "memory");
      if (lane == 0)
        __hip_atomic_store(&flB[myflag], (unsigned)(s + 1), __ATOMIC_RELAXED, __HIP_MEMORY_SCOPE_AGENT);
    }
  }
}

// ---------------------------------------------------------------- output projection + NEG pads (reads bf16 hist, applies mask)
__global__ __launch_bounds__(64) void logits_kernel(
    const unsigned short* __restrict__ hist, const int* __restrict__ lens,
    const float* __restrict__ out_w, const float* __restrict__ out_b, float* __restrict__ lg)
{
  int rw = blockIdx.x, j = threadIdx.x;
  int b = rw >> 7, t = rw & 127;
  bool mk = t < lens[b];
  float s[9];
  #pragma unroll
  for (int l = 0; l < 9; l++) s[l] = 0.f;
  if (mk) {
    size_t base = ((size_t)t * NB + b) * HD;
    const unsigned short* hf = hist + base;
    const unsigned short* hb = hist + (size_t)SEQ * NB * HD + base;
    u16x8 vf = *(const u16x8*)&hf[j * 8];
    u16x8 vb = *(const u16x8*)&hb[j * 8];
    #pragma unroll
    for (int k = 0; k < 8; k++) {
      float xf = bf2f(vf[k]), xb = bf2f(vb[k]);
      int e = j * 8 + k;
      #pragma unroll
      for (int l = 0; l < 9; l++)
        s[l] += xf * out_w[l * 1024 + e] + xb * out_w[l * 1024 + 512 + e];
    }
  }
  #pragma unroll
  for (int l = 0; l < 9; l++) {
    #pragma unroll
    for (int off = 32; off > 0; off >>= 1) s[l] += __shfl_xor(s[l], off);
  }
  float v = NEGV;
  if (j < 9) {
    float r = (j==0)?s[0]:(j==1)?s[1]:(j==2)?s[2]:(j==3)?s[3]:(j==4)?s[4]:
              (j==5)?s[5]:(j==6)?s[6]:(j==7)?s[7]:s[8];
    v = r + out_b[j];
  }
  if (j < LPAD) lg[(size_t)rw * LPAD + j] = v;
}

// ---------------------------------------------------------------- CRF gold score
__global__ __launch_bounds__(64) void crf_gold_kernel(
    const float* __restrict__ lg, const int* __restrict__ labels,
    const int* __restrict__ lens, const float* __restrict__ trn, float* __restrict__ gold)
{
  int b = blockIdx.x, j = threadIdx.x;
  int len = lens[b];
  const int* lab = labels + b * SEQ;
  const float* l0 = lg + (size_t)b * SEQ * LPAD;
  float s = 0.f;
  for (int t = j; t < SEQ; t += 64) {
    if (t < len) {
      s += l0[t * LPAD + lab[t]];
      if (t >= 1) s += trn[lab[t] * LPAD + lab[t - 1]];
    }
  }
  #pragma unroll
  for (int off = 32; off > 0; off >>= 1) s += __shfl_xor(s, off);
  if (j == 0) {
    s += trn[lab[0] * LPAD + 9];
    s += trn[10 * LPAD + lab[len - 1]];
    gold[b] = s;
  }
}

// ---------------------------------------------------------------- CRF norm + final loglik
__global__ __launch_bounds__(64) void crf_norm_kernel(
    const float* __restrict__ lg, const int* __restrict__ lens,
    const float* __restrict__ trn, const float* __restrict__ gold, float* __restrict__ out_ll)
{
  int b = blockIdx.x, i = threadIdx.x;
  int len = lens[b];
  const float* l0 = lg + (size_t)b * SEQ * LPAD;
  bool act = (i < LPAD);
  float trow[LPAD];
  #pragma unroll
  for (int jj = 0; jj < LPAD; jj++) trow[jj] = act ? trn[i * LPAD + jj] : 0.f;
  float alpha = act ? (l0[i] + trow[9]) : -1e30f;

  for (int t = 1; t < SEQ; t++) {
    float vj[LPAD];
    #pragma unroll
    for (int jj = 0; jj < LPAD; jj++) vj[jj] = __shfl(alpha, jj) + trow[jj];
    float mx = vj[0];
    #pragma unroll
    for (int jj = 1; jj < LPAD; jj++) mx = fmaxf(mx, vj[jj]);
    float sum = 0.f;
    #pragma unroll
    for (int jj = 0; jj < LPAD; jj++) sum += expf(vj[jj] - mx);
    float lgv = act ? l0[t * LPAD + i] : 0.f;
    float nw = mx + logf(sum) + lgv;
    if (act && t < len) alpha = nw;
  }
  float vj[LPAD];
  #pragma unroll
  for (int jj = 0; jj < LPAD; jj++) vj[jj] = __shfl(alpha, jj) + trn[10 * LPAD + jj];
  float mx = vj[0];
  #pragma unroll
  for (int jj = 1; jj < LPAD; jj++) mx = fmaxf(mx, vj[jj]);
  float sum = 0.f;
  #pragma unroll
  for (int jj = 0; jj < LPAD; jj++) sum += expf(vj[jj] - mx);
  if (i == 0) out_ll[b] = gold[b] - (mx + logf(sum));
}

// ================================================================ launch
extern "C" void kernel_launch(void* const* d_in, const int* in_sizes, int n_in,
                              void* d_out, int out_size, void* d_ws, size_t ws_size,
                              hipStream_t stream)
{
  (void)in_sizes; (void)n_in; (void)out_size; (void)ws_size;
  const int*   token_ids = (const int*)d_in[0];
  const int*   char_ids  = (const int*)d_in[1];
  const int*   lens      = (const int*)d_in[2];
  const int*   labels    = (const int*)d_in[3];
  const float* word_embed= (const float*)d_in[4];
  const float* char_embed= (const float*)d_in[5];
  const float* w2 = (const float*)d_in[6];  const float* cb2 = (const float*)d_in[7];
  const float* w3 = (const float*)d_in[8];  const float* cb3 = (const float*)d_in[9];
  const float* w4 = (const float*)d_in[10]; const float* cb4 = (const float*)d_in[11];
  const float* w5 = (const float*)d_in[12]; const float* cb5 = (const float*)d_in[13];
  const float* ff_w = (const float*)d_in[14]; const float* ff_b = (const float*)d_in[15];
  const float* wgate_w = (const float*)d_in[16];
  const float* cgate_w = (const float*)d_in[17];
  const float* gate_w  = (const float*)d_in[18];
  const float* wih_f = (const float*)d_in[19]; const float* whh_f = (const float*)d_in[20];
  const float* b_f   = (const float*)d_in[21];
  const float* wih_b = (const float*)d_in[22]; const float* whh_b = (const float*)d_in[23];
  const float* b_b   = (const float*)d_in[24];
  const float* out_w = (const float*)d_in[25]; const float* out_b = (const float*)d_in[26];
  const float* trn   = (const float*)d_in[27];

  char* ws = (char*)d_ws;
  size_t off = 0;
  auto alloc = [&](size_t bytes) { void* p = ws + off; off += (bytes + 255) & ~(size_t)255; return p; };
  float* ch       = (float*)alloc((size_t)NWORD * 256 * 4);
  float* word_in  = (float*)alloc((size_t)NWORD * WDIM * 4);
  float* char_in  = (float*)alloc((size_t)NWORD * WDIM * 4);
  float* t1       = (float*)alloc((size_t)NWORD * WDIM * 4);
  float* gbuf     = (float*)alloc((size_t)NWORD * WDIM * 4);
  float* feats    = (float*)alloc((size_t)NWORD * WDIM * 4);
  unsigned short* xgf = (unsigned short*)alloc((size_t)NWORD * 2048 * 2);
  unsigned short* xgb = (unsigned short*)alloc((size_t)NWORD * 2048 * 2);
  unsigned short* hist = (unsigned short*)alloc((size_t)2 * SEQ * NB * HD * 2);
  float* gold     = (float*)alloc((size_t)NB * 4);
  unsigned* flags = (unsigned*)alloc(1024);

  float* outp   = (float*)d_out;
  float* loglik = outp;
  float* logits = outp + NB;

  conv_kernel<<<NWORD, 256, 0, stream>>>(char_ids, char_embed, w2, cb2, w3, cb3, w4, cb4, w5, cb5, ch);
  gather_word_kernel<<<(NWORD * WDIM + 255) / 256, 256, 0, stream>>>(token_ids, word_embed, word_in);
  gemm_bt_kernel<<<32 * 3, 256, 0, stream>>>(ch, ff_w, ff_b, nullptr, char_in, nullptr, NWORD, 300, 256, 0, 3);
  gemm_bt_kernel<<<32 * 3, 256, 0, stream>>>(word_in, wgate_w, nullptr, nullptr, t1, nullptr, NWORD, 300, 300, 0, 3);
  gemm_bt_kernel<<<32 * 3, 256, 0, stream>>>(char_in, cgate_w, nullptr, t1, t1, nullptr, NWORD, 300, 300, 1, 3);
  gemm_bt_kernel<<<32 * 3, 256, 0, stream>>>(t1, gate_w, nullptr, nullptr, gbuf, nullptr, NWORD, 300, 300, 2, 3);
  feats_kernel<<<(NWORD * WDIM + 255) / 256, 256, 0, stream>>>(gbuf, word_in, char_in, feats, flags);
  gemm_bt_kernel<<<32 * 16, 256, 0, stream>>>(feats, wih_f, b_f, nullptr, nullptr, xgf, NWORD, 2048, 300, 0, 16);
  gemm_bt_kernel<<<32 * 16, 256, 0, stream>>>(feats, wih_b, b_b, nullptr, nullptr, xgb, NWORD, 2048, 300, 0, 16);
  {
    void* args[] = { (void*)&xgf, (void*)&xgb, (void*)&whh_f, (void*)&whh_b,
                     (void*)&lens, (void*)&hist, (void*)&flags };
    hipLaunchCooperativeKernel((void*)lstm_kernel, dim3(LSTM_BLOCKS), dim3(512), args, 0, stream);
  }
  logits_kernel<<<NWORD, 64, 0, stream>>>(hist, lens, out_w, out_b, logits);
  crf_gold_kernel<<<NB, 64, 0, stream>>>(logits, labels, lens, trn, gold);
  crf_norm_kernel<<<NB, 64, 0, stream>>>(logits, lens, trn, gold, loglik);
}

// Round 7
// 1439.360 us; speedup vs baseline: 2.2836x; 2.2836x over previous
//
#include <hip/hip_runtime.h>

#define NB    32
#define SEQ   128
#define WCH   20
#define CED   50
#define NFLT  64
#define WDIM  300
#define HD    512
#define NWORD 4096
#define LPAD  11
#define NEGV  -10000.0f
#define LSTM_BLOCKS 16

typedef float f32x4 __attribute__((ext_vector_type(4)));
typedef float f32x16 __attribute__((ext_vector_type(16)));
typedef __bf16 bf16x8 __attribute__((ext_vector_type(8)));
typedef unsigned short u16x8 __attribute__((ext_vector_type(8)));
typedef unsigned short u16x4 __attribute__((ext_vector_type(4)));
typedef unsigned long long ull;

static __device__ __forceinline__ unsigned short f2bf(float f) {
  unsigned u = __builtin_bit_cast(unsigned, f);
  u += 0x7fffu + ((u >> 16) & 1u);
  return (unsigned short)(u >> 16);
}
static __device__ __forceinline__ float bf2f(unsigned short s) {
  unsigned u = ((unsigned)s) << 16;
  return __builtin_bit_cast(float, u);
}
static __device__ __forceinline__ float sigf(float x) { return 1.0f / (1.0f + expf(-x)); }

// ---------------------------------------------------------------- char CNN
__global__ __launch_bounds__(256) void conv_kernel(
    const int* __restrict__ char_ids, const float* __restrict__ char_embed,
    const float* __restrict__ w2, const float* __restrict__ b2,
    const float* __restrict__ w3, const float* __restrict__ b3,
    const float* __restrict__ w4, const float* __restrict__ b4,
    const float* __restrict__ w5, const float* __restrict__ b5,
    float* __restrict__ ch)
{
  __shared__ __align__(16) float xT[CED][WCH];
  int wi = blockIdx.x;
  int tid = threadIdx.x;
  for (int e = tid; e < WCH * CED; e += 256) {
    int p = e / CED, c = e - p * CED;
    int cid = char_ids[wi * WCH + p];
    xT[c][p] = char_embed[cid * CED + c];
  }
  __syncthreads();
  int w = tid >> 6, f = tid & 63;
  int k = w + 2;
  int P = WCH - k + 1;
  const float* cw = (w == 0) ? w2 : (w == 1) ? w3 : (w == 2) ? w4 : w5;
  const float* cb = (w == 0) ? b2 : (w == 1) ? b3 : (w == 2) ? b4 : b5;
  float acc[19];
  #pragma unroll
  for (int p = 0; p < 19; p++) acc[p] = 0.f;
  for (int c = 0; c < CED; c++) {
    float xr[20];
    const float4* rowp = (const float4*)&xT[c][0];
    #pragma unroll
    for (int q = 0; q < 5; q++) {
      float4 v = rowp[q];
      xr[4*q+0] = v.x; xr[4*q+1] = v.y; xr[4*q+2] = v.z; xr[4*q+3] = v.w;
    }
    #pragma unroll
    for (int dw = 0; dw < 5; dw++) {
      if (dw < k) {
        float wv = cw[(dw * CED + c) * NFLT + f];
        #pragma unroll
        for (int p = 0; p < 19; p++) {
          if (p < P) acc[p] += xr[p + dw] * wv;
        }
      }
    }
  }
  float m = acc[0];
  #pragma unroll
  for (int p = 1; p < 19; p++) if (p < P) m = fmaxf(m, acc[p]);
  ch[wi * 256 + w * 64 + f] = fmaxf(0.f, m + cb[f]);
}

// ---------------------------------------------------------------- word gather
__global__ void gather_word_kernel(const int* __restrict__ token_ids,
                                   const float* __restrict__ word_embed,
                                   float* __restrict__ word_in)
{
  int idx = blockIdx.x * 256 + threadIdx.x;
  if (idx < NWORD * WDIM) {
    int i = idx / WDIM, c = idx - i * WDIM;
    word_in[idx] = word_embed[token_ids[i] * WDIM + c];
  }
}

// ---------------------------------------------------------------- generic MFMA GEMM: C = act(A @ B^T + Cin + bias)
__global__ __launch_bounds__(256) void gemm_bt_kernel(
    const float* __restrict__ A, const float* __restrict__ Bw,
    const float* __restrict__ bias, const float* __restrict__ Cin,
    float* __restrict__ Cout, unsigned short* __restrict__ Cbf,
    int M, int N, int K, int act, int gridN)
{
  __shared__ __align__(16) unsigned short As[128 * 32];
  __shared__ __align__(16) unsigned short Bs[128 * 32];
  int bid = blockIdx.x;
  int tm = bid / gridN, tn = bid - tm * gridN;
  int m0 = tm * 128, n0 = tn * 128;
  int tid = threadIdx.x;
  int lane = tid & 63, w = tid >> 6;
  int wr = (w >> 1) * 64, wc = (w & 1) * 64;
  f32x4 acc[4][4] = {};
  int fr = lane & 15, fk = (lane >> 4) * 8;

  for (int k0 = 0; k0 < K; k0 += 32) {
    __syncthreads();
    #pragma unroll
    for (int i = 0; i < 4; i++) {
      int idx = tid + i * 256;
      int r = idx >> 3, c4 = idx & 7;
      int kx = k0 + c4 * 4;
      int ra = m0 + r, rb = n0 + r;
      f32x4 av = {0.f,0.f,0.f,0.f}, bv = {0.f,0.f,0.f,0.f};
      if (kx < K) {
        if (ra < M) av = *(const f32x4*)&A[(size_t)ra * K + kx];
        if (rb < N) bv = *(const f32x4*)&Bw[(size_t)rb * K + kx];
      }
      u16x4 ap, bp;
      #pragma unroll
      for (int j = 0; j < 4; j++) { ap[j] = f2bf(av[j]); bp[j] = f2bf(bv[j]); }
      *(u16x4*)&As[r * 32 + c4 * 4] = ap;
      *(u16x4*)&Bs[r * 32 + c4 * 4] = bp;
    }
    __syncthreads();
    bf16x8 a[4], b[4];
    #pragma unroll
    for (int mt = 0; mt < 4; mt++)
      a[mt] = *(const bf16x8*)&As[(wr + mt * 16 + fr) * 32 + fk];
    #pragma unroll
    for (int nt = 0; nt < 4; nt++)
      b[nt] = *(const bf16x8*)&Bs[(wc + nt * 16 + fr) * 32 + fk];
    #pragma unroll
    for (int mt = 0; mt < 4; mt++)
      #pragma unroll
      for (int nt = 0; nt < 4; nt++)
        acc[mt][nt] = __builtin_amdgcn_mfma_f32_16x16x32_bf16(a[mt], b[nt], acc[mt][nt], 0, 0, 0);
  }

  #pragma unroll
  for (int mt = 0; mt < 4; mt++) {
    #pragma unroll
    for (int nt = 0; nt < 4; nt++) {
      #pragma unroll
      for (int j = 0; j < 4; j++) {
        int row = m0 + wr + mt * 16 + (lane >> 4) * 4 + j;
        int col = n0 + wc + nt * 16 + (lane & 15);
        if (row < M && col < N) {
          float v = acc[mt][nt][j];
          if (Cin)  v += Cin[(size_t)row * N + col];
          if (bias) v += bias[col];
          if (act == 1)      v = tanhf(v);
          else if (act == 2) v = sigf(v);
          if (Cbf) Cbf[(size_t)row * N + col] = f2bf(v);
          else     Cout[(size_t)row * N + col] = v;
        }
      }
    }
  }
}

// ---------------------------------------------------------------- gate combine (+ flag reset)
__global__ void feats_kernel(const float* __restrict__ g, const float* __restrict__ word_in,
                             const float* __restrict__ char_in, float* __restrict__ feats,
                             unsigned* __restrict__ flags)
{
  if (blockIdx.x == 0)
    __hip_atomic_store(&flags[threadIdx.x], 0u, __ATOMIC_RELAXED, __HIP_MEMORY_SCOPE_AGENT);
  int idx = blockIdx.x * 256 + threadIdx.x;
  if (idx < NWORD * WDIM) {
    float gg = g[idx];
    feats[idx] = gg * word_in[idx] + (1.f - gg) * char_in[idx];
  }
}

// ---------------------------------------------------------------- bidirectional LSTM
// 16 blocks x 512 thr; block owns units [sl*32,+32) of BOTH dirs, phases alternate F,B.
// LDS-staged h (proven r5 fabric), write-once bf16 hist, per-WAVE flags (128/dir),
// per-wave vmcnt(0)+flag publish (no post-publish barrier), wave0-only poll.
// flags[0..127]=F (sl*8+w), flags[128..255]=B. Monotonic; reset by feats_kernel.
__global__ __launch_bounds__(512) void lstm_kernel(
    const unsigned short* __restrict__ xg_f, const unsigned short* __restrict__ xg_b,
    const float* __restrict__ whh_f, const float* __restrict__ whh_b,
    const int* __restrict__ lens,
    unsigned short* __restrict__ hist, unsigned* __restrict__ flags)
{
  int sl = blockIdx.x;
  int hs0 = sl << 5;                       // 32 units per dir
  int tid = threadIdx.x, lane = tid & 63, w = tid >> 6;
  int g = w & 3, kh = w >> 2;
  int l31 = lane & 31, le = lane >> 5;

  unsigned short* histF = hist;
  unsigned short* histB = hist + (size_t)SEQ * NB * HD;
  unsigned* flF = flags;
  unsigned* flB = flags + 128;
  int myflag = sl * 8 + w;

  // B-fragments: whh row (unit) = g*HD + hs0 + l31 ; k = kh*256 + q*16 + le*8 + j
  bf16x8 wfF[16], wfB[16];
  {
    const float* sF = whh_f + (size_t)(g * HD + hs0 + l31) * HD + kh * 256 + le * 8;
    const float* sB = whh_b + (size_t)(g * HD + hs0 + l31) * HD + kh * 256 + le * 8;
    #pragma unroll
    for (int q = 0; q < 16; q++) {
      u16x8 tf_, tb_;
      #pragma unroll
      for (int j = 0; j < 8; j++) { tf_[j] = f2bf(sF[q * 16 + j]); tb_[j] = f2bf(sB[q * 16 + j]); }
      wfF[q] = __builtin_bit_cast(bf16x8, tf_);
      wfB[q] = __builtin_bit_cast(bf16x8, tb_);
    }
  }

  __shared__ __align__(16) unsigned short hS[16384];   // 32KB fragment-major (shared F/B)
  __shared__ float Gs[2][2][NB][132];                  // [dir][kh][batch][g*32+col]

  int b = tid >> 4, up = tid & 15;         // update: batch, unit-pair
  int srow = tid >> 4, sq = tid & 15;      // staging: h row (batch), 64B quad
  int mylen = lens[b];
  float cF[2] = {0.f,0.f}, hpF[2] = {0.f,0.f};
  float cB[2] = {0.f,0.f}, hpB[2] = {0.f,0.f};
  ull hr[8];                               // staging regs (time-shared F/B)

  auto stage_issue = [&](const unsigned short* hbuf) {
    const ull* hq = (const ull*)hbuf;
    #pragma unroll
    for (int i = 0; i < 8; i++)
      hr[i] = __hip_atomic_load(hq + srow * 128 + sq * 8 + i, __ATOMIC_RELAXED, __HIP_MEMORY_SCOPE_AGENT);
  };
  auto stage_write = [&]() {
    int rs = ((srow ^ (sq & 7)) & 31) << 4;
    #pragma unroll
    for (int e2 = 0; e2 < 4; e2++) {
      int kk = 2 * sq + (e2 >> 1), e = e2 & 1;
      uint4 qv;
      qv.x = (unsigned)hr[2*e2];   qv.y = (unsigned)(hr[2*e2] >> 32);
      qv.z = (unsigned)hr[2*e2+1]; qv.w = (unsigned)(hr[2*e2+1] >> 32);
      *(uint4*)((char*)hS + (((kk * 2 + e) << 9) + rs)) = qv;
    }
  };
  // wave0-only: lane-parallel poll of all 128 flags (64 lanes x 1 ull)
  auto pollflags = [&](const unsigned* fl, unsigned tgt) {
    const ull* fp = (const ull*)fl;
    for (;;) {
      ull v = __hip_atomic_load(fp + lane, __ATOMIC_RELAXED, __HIP_MEMORY_SCOPE_AGENT);
      bool ok = ((unsigned)v >= tgt) && ((unsigned)(v >> 32) >= tgt);
      if (__all(ok)) break;
    }
  };

  // xg preload for s=0
  unsigned xF[4], xB[4];
  {
    const unsigned* pF = (const unsigned*)xg_f;
    const unsigned* pB = (const unsigned*)xg_b;
    size_t oF = (size_t)(b * SEQ + 0) * 1024 + (hs0 >> 1) + up;
    size_t oB = (size_t)(b * SEQ + (SEQ - 1)) * 1024 + (hs0 >> 1) + up;
    #pragma unroll
    for (int g4 = 0; g4 < 4; g4++) { xF[g4] = pF[oF + g4 * 256]; xB[g4] = pB[oB + g4 * 256]; }
  }

  for (int s = 0; s < SEQ; s++) {
    int tb_ = SEQ - 1 - s;
    // ================= F phase =================
    if (s > 0) stage_write();                 // f-h(s-1) regs -> LDS
    __syncthreads();                          // S1
    {
      f32x16 acc = {};
      if (s > 0) {
        #pragma unroll
        for (int q = 0; q < 16; q++) {
          int kk = kh * 16 + q;
          int rs = ((l31 ^ ((kk >> 1) & 7)) & 31) << 4;
          bf16x8 a = *(const bf16x8*)((const char*)hS + (((kk * 2 + le) << 9) + rs));
          acc = __builtin_amdgcn_mfma_f32_32x32x16_bf16(a, wfF[q], acc, 0, 0, 0);
        }
      }
      #pragma unroll
      for (int r = 0; r < 16; r++) {
        int row = (r & 3) + 8 * (r >> 2) + 4 * le;
        Gs[0][kh][row][g * 32 + l31] = acc[r];
      }
    }
    if (s > 0 && w == 0) pollflags(flB, (unsigned)s);   // b-waves done with step s
    __syncthreads();                          // S2: Gs ready + detect released
    if (s > 0) stage_issue(histB + ((size_t)(s - 1) * NB) * HD);  // b-h(s-1) -> regs
    {
      bool mk = (s < mylen);
      float pre[4][2];
      #pragma unroll
      for (int g4 = 0; g4 < 4; g4++) {
        float2 p0 = *(const float2*)&Gs[0][0][b][g4 * 32 + 2 * up];
        float2 p1 = *(const float2*)&Gs[0][1][b][g4 * 32 + 2 * up];
        pre[g4][0] = p0.x + p1.x; pre[g4][1] = p0.y + p1.y;
      }
      unsigned pk = 0;
      #pragma unroll
      for (int j = 0; j < 2; j++) {
        float xi = bf2f((unsigned short)(xF[0] >> (16*j)));
        float xf = bf2f((unsigned short)(xF[1] >> (16*j)));
        float xG = bf2f((unsigned short)(xF[2] >> (16*j)));
        float xo = bf2f((unsigned short)(xF[3] >> (16*j)));
        float iv = sigf(xi + pre[0][j]);
        float fv = sigf(xf + pre[1][j]);
        float Gv = tanhf(xG + pre[2][j]);
        float o_ = sigf(xo + pre[3][j]);
        float cn = fv * cF[j] + iv * Gv;
        float hh = o_ * tanhf(cn);
        if (mk) cF[j] = cn;
        float hk = mk ? hh : hpF[j];
        hpF[j] = hk;
        pk |= ((unsigned)f2bf(hk)) << (16*j);
      }
      unsigned* hd = (unsigned*)histF;
      __hip_atomic_store(&hd[(((size_t)s * NB + b) * HD + hs0 + 2 * up) >> 1], pk,
                         __ATOMIC_RELAXED, __HIP_MEMORY_SCOPE_AGENT);
    }
    asm volatile("s_waitcnt vmcnt(0)" ::: "memory");   // this wave's hist stores at L3
    if (lane == 0)
      __hip_atomic_store(&flF[myflag], (unsigned)(s + 1), __ATOMIC_RELAXED, __HIP_MEMORY_SCOPE_AGENT);
    if (s + 1 < SEQ) {                        // xF prefetch (after flag: not in drain)
      const unsigned* pF = (const unsigned*)xg_f;
      size_t o = (size_t)(b * SEQ + (s + 1)) * 1024 + (hs0 >> 1) + up;
      xF[0] = pF[o]; xF[1] = pF[o + 256]; xF[2] = pF[o + 512]; xF[3] = pF[o + 768];
    }
    // ================= B phase =================
    if (s > 0) stage_write();                 // b-h(s-1) regs -> LDS
    __syncthreads();                          // S1
    {
      f32x16 acc = {};
      if (s > 0) {
        #pragma unroll
        for (int q = 0; q < 16; q++) {
          int kk = kh * 16 + q;
          int rs = ((l31 ^ ((kk >> 1) & 7)) & 31) << 4;
          bf16x8 a = *(const bf16x8*)((const char*)hS + (((kk * 2 + le) << 9) + rs));
          acc = __builtin_amdgcn_mfma_f32_32x32x16_bf16(a, wfB[q], acc, 0, 0, 0);
        }
      }
      #pragma unroll
      for (int r = 0; r < 16; r++) {
        int row = (r & 3) + 8 * (r >> 2) + 4 * le;
        Gs[1][kh][row][g * 32 + l31] = acc[r];
      }
    }
    if (s + 1 < SEQ && w == 0) pollflags(flF, (unsigned)(s + 1));  // f-waves done step s+1
    __syncthreads();                          // S2
    if (s + 1 < SEQ) stage_issue(histF + ((size_t)s * NB) * HD);   // f-h(s) -> regs
    {
      bool mk = (tb_ < mylen);
      float pre[4][2];
      #pragma unroll
      for (int g4 = 0; g4 < 4; g4++) {
        float2 p0 = *(const float2*)&Gs[1][0][b][g4 * 32 + 2 * up];
        float2 p1 = *(const float2*)&Gs[1][1][b][g4 * 32 + 2 * up];
        pre[g4][0] = p0.x + p1.x; pre[g4][1] = p0.y + p1.y;
      }
      unsigned pk = 0;
      #pragma unroll
      for (int j = 0; j < 2; j++) {
        float xi = bf2f((unsigned short)(xB[0] >> (16*j)));
        float xf = bf2f((unsigned short)(xB[1] >> (16*j)));
        float xG = bf2f((unsigned short)(xB[2] >> (16*j)));
        float xo = bf2f((unsigned short)(xB[3] >> (16*j)));
        float iv = sigf(xi + pre[0][j]);
        float fv = sigf(xf + pre[1][j]);
        float Gv = tanhf(xG + pre[2][j]);
        float o_ = sigf(xo + pre[3][j]);
        float cn = fv * cB[j] + iv * Gv;
        float hh = o_ * tanhf(cn);
        if (mk) cB[j] = cn;
        float hk = mk ? hh : hpB[j];
        hpB[j] = hk;
        pk |= ((unsigned)f2bf(hk)) << (16*j);
      }
      unsigned* hd = (unsigned*)histB;
      __hip_atomic_store(&hd[(((size_t)s * NB + b) * HD + hs0 + 2 * up) >> 1], pk,
                         __ATOMIC_RELAXED, __HIP_MEMORY_SCOPE_AGENT);
    }
    asm volatile("s_waitcnt vmcnt(0)" ::: "memory");
    if (lane == 0)
      __hip_atomic_store(&flB[myflag], (unsigned)(s + 1), __ATOMIC_RELAXED, __HIP_MEMORY_SCOPE_AGENT);
    if (s + 1 < SEQ) {
      const unsigned* pB = (const unsigned*)xg_b;
      size_t o = (size_t)(b * SEQ + (SEQ - 2 - s)) * 1024 + (hs0 >> 1) + up;
      xB[0] = pB[o]; xB[1] = pB[o + 256]; xB[2] = pB[o + 512]; xB[3] = pB[o + 768];
    }
  }
}

// ---------------------------------------------------------------- output projection + NEG pads (reads bf16 hist, applies mask)
__global__ __launch_bounds__(64) void logits_kernel(
    const unsigned short* __restrict__ hist, const int* __restrict__ lens,
    const float* __restrict__ out_w, const float* __restrict__ out_b, float* __restrict__ lg)
{
  int rw = blockIdx.x, j = threadIdx.x;
  int b = rw >> 7, t = rw & 127;
  bool mk = t < lens[b];
  float s[9];
  #pragma unroll
  for (int l = 0; l < 9; l++) s[l] = 0.f;
  if (mk) {
    size_t base = ((size_t)t * NB + b) * HD;
    const unsigned short* hf = hist + base;
    const unsigned short* hb = hist + (size_t)SEQ * NB * HD + base;
    u16x8 vf = *(const u16x8*)&hf[j * 8];
    u16x8 vb = *(const u16x8*)&hb[j * 8];
    #pragma unroll
    for (int k = 0; k < 8; k++) {
      float xf = bf2f(vf[k]), xb = bf2f(vb[k]);
      int e = j * 8 + k;
      #pragma unroll
      for (int l = 0; l < 9; l++)
        s[l] += xf * out_w[l * 1024 + e] + xb * out_w[l * 1024 + 512 + e];
    }
  }
  #pragma unroll
  for (int l = 0; l < 9; l++) {
    #pragma unroll
    for (int off = 32; off > 0; off >>= 1) s[l] += __shfl_xor(s[l], off);
  }
  float v = NEGV;
  if (j < 9) {
    float r = (j==0)?s[0]:(j==1)?s[1]:(j==2)?s[2]:(j==3)?s[3]:(j==4)?s[4]:
              (j==5)?s[5]:(j==6)?s[6]:(j==7)?s[7]:s[8];
    v = r + out_b[j];
  }
  if (j < LPAD) lg[(size_t)rw * LPAD + j] = v;
}

// ---------------------------------------------------------------- CRF gold score
__global__ __launch_bounds__(64) void crf_gold_kernel(
    const float* __restrict__ lg, const int* __restrict__ labels,
    const int* __restrict__ lens, const float* __restrict__ trn, float* __restrict__ gold)
{
  int b = blockIdx.x, j = threadIdx.x;
  int len = lens[b];
  const int* lab = labels + b * SEQ;
  const float* l0 = lg + (size_t)b * SEQ * LPAD;
  float s = 0.f;
  for (int t = j; t < SEQ; t += 64) {
    if (t < len) {
      s += l0[t * LPAD + lab[t]];
      if (t >= 1) s += trn[lab[t] * LPAD + lab[t - 1]];
    }
  }
  #pragma unroll
  for (int off = 32; off > 0; off >>= 1) s += __shfl_xor(s, off);
  if (j == 0) {
    s += trn[lab[0] * LPAD + 9];
    s += trn[10 * LPAD + lab[len - 1]];
    gold[b] = s;
  }
}

// ---------------------------------------------------------------- CRF norm + final loglik
__global__ __launch_bounds__(64) void crf_norm_kernel(
    const float* __restrict__ lg, const int* __restrict__ lens,
    const float* __restrict__ trn, const float* __restrict__ gold, float* __restrict__ out_ll)
{
  int b = blockIdx.x, i = threadIdx.x;
  int len = lens[b];
  const float* l0 = lg + (size_t)b * SEQ * LPAD;
  bool act = (i < LPAD);
  float trow[LPAD];
  #pragma unroll
  for (int jj = 0; jj < LPAD; jj++) trow[jj] = act ? trn[i * LPAD + jj] : 0.f;
  float alpha = act ? (l0[i] + trow[9]) : -1e30f;

  for (int t = 1; t < SEQ; t++) {
    float vj[LPAD];
    #pragma unroll
    for (int jj = 0; jj < LPAD; jj++) vj[jj] = __shfl(alpha, jj) + trow[jj];
    float mx = vj[0];
    #pragma unroll
    for (int jj = 1; jj < LPAD; jj++) mx = fmaxf(mx, vj[jj]);
    float sum = 0.f;
    #pragma unroll
    for (int jj = 0; jj < LPAD; jj++) sum += expf(vj[jj] - mx);
    float lgv = act ? l0[t * LPAD + i] : 0.f;
    float nw = mx + logf(sum) + lgv;
    if (act && t < len) alpha = nw;
  }
  float vj[LPAD];
  #pragma unroll
  for (int jj = 0; jj < LPAD; jj++) vj[jj] = __shfl(alpha, jj) + trn[10 * LPAD + jj];
  float mx = vj[0];
  #pragma unroll
  for (int jj = 1; jj < LPAD; jj++) mx = fmaxf(mx, vj[jj]);
  float sum = 0.f;
  #pragma unroll
  for (int jj = 0; jj < LPAD; jj++) sum += expf(vj[jj] - mx);
  if (i == 0) out_ll[b] = gold[b] - (mx + logf(sum));
}

// ================================================================ launch
extern "C" void kernel_launch(void* const* d_in, const int* in_sizes, int n_in,
                              void* d_out, int out_size, void* d_ws, size_t ws_size,
                              hipStream_t stream)
{
  (void)in_sizes; (void)n_in; (void)out_size; (void)ws_size;
  const int*   token_ids = (const int*)d_in[0];
  const int*   char_ids  = (const int*)d_in[1];
  const int*   lens      = (const int*)d_in[2];
  const int*   labels    = (const int*)d_in[3];
  const float* word_embed= (const float*)d_in[4];
  const float* char_embed= (const float*)d_in[5];
  const float* w2 = (const float*)d_in[6];  const float* cb2 = (const float*)d_in[7];
  const float* w3 = (const float*)d_in[8];  const float* cb3 = (const float*)d_in[9];
  const float* w4 = (const float*)d_in[10]; const float* cb4 = (const float*)d_in[11];
  const float* w5 = (const float*)d_in[12]; const float* cb5 = (const float*)d_in[13];
  const float* ff_w = (const float*)d_in[14]; const float* ff_b = (const float*)d_in[15];
  const float* wgate_w = (const float*)d_in[16];
  const float* cgate_w = (const float*)d_in[17];
  const float* gate_w  = (const float*)d_in[18];
  const float* wih_f = (const float*)d_in[19]; const float* whh_f = (const float*)d_in[20];
  const float* b_f   = (const float*)d_in[21];
  const float* wih_b = (const float*)d_in[22]; const float* whh_b = (const float*)d_in[23];
  const float* b_b   = (const float*)d_in[24];
  const float* out_w = (const float*)d_in[25]; const float* out_b = (const float*)d_in[26];
  const float* trn   = (const float*)d_in[27];

  char* ws = (char*)d_ws;
  size_t off = 0;
  auto alloc = [&](size_t bytes) { void* p = ws + off; off += (bytes + 255) & ~(size_t)255; return p; };
  float* ch       = (float*)alloc((size_t)NWORD * 256 * 4);
  float* word_in  = (float*)alloc((size_t)NWORD * WDIM * 4);
  float* char_in  = (float*)alloc((size_t)NWORD * WDIM * 4);
  float* t1       = (float*)alloc((size_t)NWORD * WDIM * 4);
  float* gbuf     = (float*)alloc((size_t)NWORD * WDIM * 4);
  float* feats    = (float*)alloc((size_t)NWORD * WDIM * 4);
  unsigned short* xgf = (unsigned short*)alloc((size_t)NWORD * 2048 * 2);
  unsigned short* xgb = (unsigned short*)alloc((size_t)NWORD * 2048 * 2);
  unsigned short* hist = (unsigned short*)alloc((size_t)2 * SEQ * NB * HD * 2);
  float* gold     = (float*)alloc((size_t)NB * 4);
  unsigned* flags = (unsigned*)alloc(1024);

  float* outp   = (float*)d_out;
  float* loglik = outp;
  float* logits = outp + NB;

  conv_kernel<<<NWORD, 256, 0, stream>>>(char_ids, char_embed, w2, cb2, w3, cb3, w4, cb4, w5, cb5, ch);
  gather_word_kernel<<<(NWORD * WDIM + 255) / 256, 256, 0, stream>>>(token_ids, word_embed, word_in);
  gemm_bt_kernel<<<32 * 3, 256, 0, stream>>>(ch, ff_w, ff_b, nullptr, char_in, nullptr, NWORD, 300, 256, 0, 3);
  gemm_bt_kernel<<<32 * 3, 256, 0, stream>>>(word_in, wgate_w, nullptr, nullptr, t1, nullptr, NWORD, 300, 300, 0, 3);
  gemm_bt_kernel<<<32 * 3, 256, 0, stream>>>(char_in, cgate_w, nullptr, t1, t1, nullptr, NWORD, 300, 300, 1, 3);
  gemm_bt_kernel<<<32 * 3, 256, 0, stream>>>(t1, gate_w, nullptr, nullptr, gbuf, nullptr, NWORD, 300, 300, 2, 3);
  feats_kernel<<<(NWORD * WDIM + 255) / 256, 256, 0, stream>>>(gbuf, word_in, char_in, feats, flags);
  gemm_bt_kernel<<<32 * 16, 256, 0, stream>>>(feats, wih_f, b_f, nullptr, nullptr, xgf, NWORD, 2048, 300, 0, 16);
  gemm_bt_kernel<<<32 * 16, 256, 0, stream>>>(feats, wih_b, b_b, nullptr, nullptr, xgb, NWORD, 2048, 300, 0, 16);
  {
    void* args[] = { (void*)&xgf, (void*)&xgb, (void*)&whh_f, (void*)&whh_b,
                     (void*)&lens, (void*)&hist, (void*)&flags };
    hipLaunchCooperativeKernel((void*)lstm_kernel, dim3(LSTM_BLOCKS), dim3(512), args, 0, stream);
  }
  logits_kernel<<<NWORD, 64, 0, stream>>>(hist, lens, out_w, out_b, logits);
  crf_gold_kernel<<<NB, 64, 0, stream>>>(logits, labels, lens, trn, gold);
  crf_norm_kernel<<<NB, 64, 0, stream>>>(logits, lens, trn, gold, loglik);
}

// Round 8
// 1282.792 us; speedup vs baseline: 2.5624x; 1.1221x over previous
//
#include <hip/hip_runtime.h>

#define NB    32
#define SEQ   128
#define WCH   20
#define CED   50
#define NFLT  64
#define WDIM  300
#define HD    512
#define NWORD 4096
#define LPAD  11
#define NEGV  -10000.0f
#define LSTM_BLOCKS 16

typedef float f32x4 __attribute__((ext_vector_type(4)));
typedef float f32x16 __attribute__((ext_vector_type(16)));
typedef __bf16 bf16x8 __attribute__((ext_vector_type(8)));
typedef unsigned short u16x8 __attribute__((ext_vector_type(8)));
typedef unsigned short u16x4 __attribute__((ext_vector_type(4)));
typedef unsigned long long ull;

static __device__ __forceinline__ unsigned short f2bf(float f) {
  unsigned u = __builtin_bit_cast(unsigned, f);
  u += 0x7fffu + ((u >> 16) & 1u);
  return (unsigned short)(u >> 16);
}
static __device__ __forceinline__ float bf2f(unsigned short s) {
  unsigned u = ((unsigned)s) << 16;
  return __builtin_bit_cast(float, u);
}
static __device__ __forceinline__ float sigf(float x) { return 1.0f / (1.0f + expf(-x)); }

// ---------------------------------------------------------------- char CNN
__global__ __launch_bounds__(256) void conv_kernel(
    const int* __restrict__ char_ids, const float* __restrict__ char_embed,
    const float* __restrict__ w2, const float* __restrict__ b2,
    const float* __restrict__ w3, const float* __restrict__ b3,
    const float* __restrict__ w4, const float* __restrict__ b4,
    const float* __restrict__ w5, const float* __restrict__ b5,
    float* __restrict__ ch)
{
  __shared__ __align__(16) float xT[CED][WCH];
  int wi = blockIdx.x;
  int tid = threadIdx.x;
  for (int e = tid; e < WCH * CED; e += 256) {
    int p = e / CED, c = e - p * CED;
    int cid = char_ids[wi * WCH + p];
    xT[c][p] = char_embed[cid * CED + c];
  }
  __syncthreads();
  int w = tid >> 6, f = tid & 63;
  int k = w + 2;
  int P = WCH - k + 1;
  const float* cw = (w == 0) ? w2 : (w == 1) ? w3 : (w == 2) ? w4 : w5;
  const float* cb = (w == 0) ? b2 : (w == 1) ? b3 : (w == 2) ? b4 : b5;
  float acc[19];
  #pragma unroll
  for (int p = 0; p < 19; p++) acc[p] = 0.f;
  for (int c = 0; c < CED; c++) {
    float xr[20];
    const float4* rowp = (const float4*)&xT[c][0];
    #pragma unroll
    for (int q = 0; q < 5; q++) {
      float4 v = rowp[q];
      xr[4*q+0] = v.x; xr[4*q+1] = v.y; xr[4*q+2] = v.z; xr[4*q+3] = v.w;
    }
    #pragma unroll
    for (int dw = 0; dw < 5; dw++) {
      if (dw < k) {
        float wv = cw[(dw * CED + c) * NFLT + f];
        #pragma unroll
        for (int p = 0; p < 19; p++) {
          if (p < P) acc[p] += xr[p + dw] * wv;
        }
      }
    }
  }
  float m = acc[0];
  #pragma unroll
  for (int p = 1; p < 19; p++) if (p < P) m = fmaxf(m, acc[p]);
  ch[wi * 256 + w * 64 + f] = fmaxf(0.f, m + cb[f]);
}

// ---------------------------------------------------------------- word gather
__global__ void gather_word_kernel(const int* __restrict__ token_ids,
                                   const float* __restrict__ word_embed,
                                   float* __restrict__ word_in)
{
  int idx = blockIdx.x * 256 + threadIdx.x;
  if (idx < NWORD * WDIM) {
    int i = idx / WDIM, c = idx - i * WDIM;
    word_in[idx] = word_embed[token_ids[i] * WDIM + c];
  }
}

// ---------------------------------------------------------------- generic MFMA GEMM: C = act(A @ B^T + Cin + bias)
__global__ __launch_bounds__(256) void gemm_bt_kernel(
    const float* __restrict__ A, const float* __restrict__ Bw,
    const float* __restrict__ bias, const float* __restrict__ Cin,
    float* __restrict__ Cout, unsigned short* __restrict__ Cbf,
    int M, int N, int K, int act, int gridN)
{
  __shared__ __align__(16) unsigned short As[128 * 32];
  __shared__ __align__(16) unsigned short Bs[128 * 32];
  int bid = blockIdx.x;
  int tm = bid / gridN, tn = bid - tm * gridN;
  int m0 = tm * 128, n0 = tn * 128;
  int tid = threadIdx.x;
  int lane = tid & 63, w = tid >> 6;
  int wr = (w >> 1) * 64, wc = (w & 1) * 64;
  f32x4 acc[4][4] = {};
  int fr = lane & 15, fk = (lane >> 4) * 8;

  for (int k0 = 0; k0 < K; k0 += 32) {
    __syncthreads();
    #pragma unroll
    for (int i = 0; i < 4; i++) {
      int idx = tid + i * 256;
      int r = idx >> 3, c4 = idx & 7;
      int kx = k0 + c4 * 4;
      int ra = m0 + r, rb = n0 + r;
      f32x4 av = {0.f,0.f,0.f,0.f}, bv = {0.f,0.f,0.f,0.f};
      if (kx < K) {
        if (ra < M) av = *(const f32x4*)&A[(size_t)ra * K + kx];
        if (rb < N) bv = *(const f32x4*)&Bw[(size_t)rb * K + kx];
      }
      u16x4 ap, bp;
      #pragma unroll
      for (int j = 0; j < 4; j++) { ap[j] = f2bf(av[j]); bp[j] = f2bf(bv[j]); }
      *(u16x4*)&As[r * 32 + c4 * 4] = ap;
      *(u16x4*)&Bs[r * 32 + c4 * 4] = bp;
    }
    __syncthreads();
    bf16x8 a[4], b[4];
    #pragma unroll
    for (int mt = 0; mt < 4; mt++)
      a[mt] = *(const bf16x8*)&As[(wr + mt * 16 + fr) * 32 + fk];
    #pragma unroll
    for (int nt = 0; nt < 4; nt++)
      b[nt] = *(const bf16x8*)&Bs[(wc + nt * 16 + fr) * 32 + fk];
    #pragma unroll
    for (int mt = 0; mt < 4; mt++)
      #pragma unroll
      for (int nt = 0; nt < 4; nt++)
        acc[mt][nt] = __builtin_amdgcn_mfma_f32_16x16x32_bf16(a[mt], b[nt], acc[mt][nt], 0, 0, 0);
  }

  #pragma unroll
  for (int mt = 0; mt < 4; mt++) {
    #pragma unroll
    for (int nt = 0; nt < 4; nt++) {
      #pragma unroll
      for (int j = 0; j < 4; j++) {
        int row = m0 + wr + mt * 16 + (lane >> 4) * 4 + j;
        int col = n0 + wc + nt * 16 + (lane & 15);
        if (row < M && col < N) {
          float v = acc[mt][nt][j];
          if (Cin)  v += Cin[(size_t)row * N + col];
          if (bias) v += bias[col];
          if (act == 1)      v = tanhf(v);
          else if (act == 2) v = sigf(v);
          if (Cbf) Cbf[(size_t)row * N + col] = f2bf(v);
          else     Cout[(size_t)row * N + col] = v;
        }
      }
    }
  }
}

// ---------------------------------------------------------------- gate combine (+ flag reset)
__global__ void feats_kernel(const float* __restrict__ g, const float* __restrict__ word_in,
                             const float* __restrict__ char_in, float* __restrict__ feats,
                             unsigned* __restrict__ flags)
{
  if (blockIdx.x == 0 && threadIdx.x < 32)
    __hip_atomic_store(&flags[threadIdx.x], 0u, __ATOMIC_RELAXED, __HIP_MEMORY_SCOPE_AGENT);
  int idx = blockIdx.x * 256 + threadIdx.x;
  if (idx < NWORD * WDIM) {
    float gg = g[idx];
    feats[idx] = gg * word_in[idx] + (1.f - gg) * char_in[idx];
  }
}

// ---------------------------------------------------------------- bidirectional LSTM (r4-proven fabric)
// 16 blocks x 512 thr: dir = bid>>3, slice = bid&7 (64 hidden units).
// Wave w: gate g=w&3, 32-col chunk hc=w>>2. whh VGPR-resident 32x32x16 B-fragments.
// h exchanged via agent-scope (L3-coherent) atomics; per-block flags, block-wide drain.
// r8 changes vs r4: (1) wave0 lane-parallel flag poll (1 L3 RT/iter vs 4 serialized);
//                   (2) lstm_out store moved after flag publish (off the drain path).
__global__ __launch_bounds__(512, 2) void lstm_kernel(
    const unsigned short* __restrict__ xg_f, const unsigned short* __restrict__ xg_b,
    const float* __restrict__ whh_f, const float* __restrict__ whh_b,
    const int* __restrict__ lens,
    float* __restrict__ lstm_out, unsigned short* __restrict__ h_glob,
    unsigned* __restrict__ flags)
{
  int bid = blockIdx.x;
  int dir = bid >> 3, sl = bid & 7;
  int hs0 = sl << 6;                       // 64 hidden units per block
  int tid = threadIdx.x, lane = tid & 63, w = tid >> 6;
  int g = w & 3, hc = w >> 2;              // gate, 32-unit chunk
  int l31 = lane & 31, le = lane >> 5;     // A-row / D-col, k-half
  const unsigned short* xg = dir ? xg_b : xg_f;
  const float* whh = dir ? whh_b : whh_f;
  unsigned short* hg = h_glob + dir * (2 * NB * HD);
  unsigned* myflags = flags + dir * 16;

  // B-fragments: wf[kk] = whh rows (units) g*512+hs0+hc*32+l31, k = kk*16 + le*8 + j
  bf16x8 wf[32];
  {
    const float* src = whh + (size_t)(g * HD + hs0 + hc * 32 + l31) * HD + le * 8;
    #pragma unroll
    for (int kk = 0; kk < 32; kk++) {
      u16x8 tv;
      #pragma unroll
      for (int j = 0; j < 8; j++) tv[j] = f2bf(src[kk * 16 + j]);
      wf[kk] = __builtin_bit_cast(bf16x8, tv);
    }
  }

  __shared__ __align__(16) unsigned short hS[16384];   // 32KB fragment-major
  __shared__ float Gs[NB][260];                        // [batch][gate*64 + unit]

  int b = tid >> 4;                        // batch
  int u = (tid & 15) << 2;                 // 4 units per thread
  int srow = tid >> 4, sq = tid & 15;      // staging mapping
  int mylen = lens[b];
  float c4[4] = {0.f,0.f,0.f,0.f}, hp4[4] = {0.f,0.f,0.f,0.f};

  // preload xg for s=0
  ull xq0, xq1, xq2, xq3;
  {
    int t0 = dir ? (SEQ - 1) : 0;
    const ull* xp = (const ull*)&xg[((size_t)(b * SEQ + t0)) * 2048 + hs0 + u];
    xq0 = xp[0]; xq1 = xp[128]; xq2 = xp[256]; xq3 = xp[384];
  }

  for (int s = 0; s < SEQ; s++) {
    int t = dir ? (SEQ - 1 - s) : s;
    f32x16 acc0 = {}, acc1 = {};

    if (s > 0) {
      // ---- wait for all 8 producers of this dir to publish h(s-1): wave0, lane-parallel
      if (w == 0) {
        unsigned tgt = (unsigned)s;
        for (;;) {
          unsigned v = (lane < 8)
            ? __hip_atomic_load(&myflags[lane], __ATOMIC_RELAXED, __HIP_MEMORY_SCOPE_AGENT)
            : tgt;
          if (__all(v >= tgt)) break;
          __builtin_amdgcn_s_sleep(1);
        }
      }
      __syncthreads();                       // B1: release all waves
      // ---- stage h(s-1) -> LDS, fragment-major (64B/thread)
      {
        const ull* hq = (const ull*)(hg + (s & 1) * (NB * HD));
        ull v[8];
        #pragma unroll
        for (int i = 0; i < 8; i++)
          v[i] = __hip_atomic_load(hq + srow * 128 + sq * 8 + i, __ATOMIC_RELAXED, __HIP_MEMORY_SCOPE_AGENT);
        int rs = ((srow ^ (sq & 7)) & 31) << 4;
        #pragma unroll
        for (int e2 = 0; e2 < 4; e2++) {
          int kk = 2 * sq + (e2 >> 1), e = e2 & 1;
          uint4 qv;
          qv.x = (unsigned)v[2*e2];     qv.y = (unsigned)(v[2*e2] >> 32);
          qv.z = (unsigned)v[2*e2+1];   qv.w = (unsigned)(v[2*e2+1] >> 32);
          *(uint4*)((char*)hS + (((kk * 2 + e) << 9) + rs)) = qv;
        }
      }
      __syncthreads();                       // B2
      // ---- MFMA: acc[batch][unit] += h(s-1) @ whh^T
      #pragma unroll
      for (int kk = 0; kk < 32; kk += 2) {
        int rs = ((l31 ^ ((kk >> 1) & 7)) & 31) << 4;
        int a0off = ((kk * 2 + le) << 9) + rs;
        int a1off = ((kk * 2 + 2 + le) << 9) + rs;
        bf16x8 a0 = *(const bf16x8*)((const char*)hS + a0off);
        bf16x8 a1 = *(const bf16x8*)((const char*)hS + a1off);
        acc0 = __builtin_amdgcn_mfma_f32_32x32x16_bf16(a0, wf[kk], acc0, 0, 0, 0);
        acc1 = __builtin_amdgcn_mfma_f32_32x32x16_bf16(a1, wf[kk+1], acc1, 0, 0, 0);
      }
    }

    // ---- scatter gate pre-activations to Gs
    #pragma unroll
    for (int r = 0; r < 16; r++) {
      int bb = (r & 3) + 8 * (r >> 2) + 4 * le;
      Gs[bb][g * 64 + hc * 32 + l31] = acc0[r] + acc1[r];
    }
    __syncthreads();                         // B3

    // ---- state update: 4 units per thread
    f32x4 gi  = *(const f32x4*)&Gs[b][u];
    f32x4 gfv = *(const f32x4*)&Gs[b][64 + u];
    f32x4 ggv = *(const f32x4*)&Gs[b][128 + u];
    f32x4 gov = *(const f32x4*)&Gs[b][192 + u];
    bool mk = (t < mylen);
    f32x4 outv;
    ull hpk = 0;
    #pragma unroll
    for (int j = 0; j < 4; j++) {
      float xi = bf2f((unsigned short)(xq0 >> (16*j)));
      float xf = bf2f((unsigned short)(xq1 >> (16*j)));
      float xG = bf2f((unsigned short)(xq2 >> (16*j)));
      float xo = bf2f((unsigned short)(xq3 >> (16*j)));
      float iv = sigf(xi + gi[j]);
      float fv = sigf(xf + gfv[j]);
      float Gv = tanhf(xG + ggv[j]);
      float ov = sigf(xo + gov[j]);
      float cn = fv * c4[j] + iv * Gv;
      float hn = ov * tanhf(cn);
      if (mk) c4[j] = cn;
      float hk = mk ? hn : hp4[j];
      hp4[j] = hk;
      outv[j] = mk ? hn : 0.f;
      hpk |= ((ull)f2bf(hk)) << (16*j);
    }
    // publish h (bypass store, coherent at L3) — the only store the drain must cover
    {
      ull* hd = (ull*)(hg + ((s & 1) ^ 1) * (NB * HD));
      __hip_atomic_store(&hd[(b * HD + hs0 + u) >> 2], hpk, __ATOMIC_RELAXED, __HIP_MEMORY_SCOPE_AGENT);
    }

    __syncthreads();                         // B4: drains all waves' h stores to L3
    if (tid == 0)
      __hip_atomic_store(&myflags[sl], (unsigned)(s + 1), __ATOMIC_RELAXED, __HIP_MEMORY_SCOPE_AGENT);

    // ---- off-critical-path work: lstm_out store + next-step xg prefetch
    size_t obase = ((size_t)(b * SEQ + t)) * 1024 + dir * HD + hs0 + u;
    *(f32x4*)&lstm_out[obase] = outv;
    if (s + 1 < SEQ) {
      int tn = dir ? (SEQ - 2 - s) : (s + 1);
      const ull* xp = (const ull*)&xg[((size_t)(b * SEQ + tn)) * 2048 + hs0 + u];
      xq0 = xp[0]; xq1 = xp[128]; xq2 = xp[256]; xq3 = xp[384];
    }
  }
}

// ---------------------------------------------------------------- output projection + NEG pads
__global__ __launch_bounds__(64) void logits_kernel(
    const float* __restrict__ lstm_out, const float* __restrict__ out_w,
    const float* __restrict__ out_b, float* __restrict__ lg)
{
  int rw = blockIdx.x, j = threadIdx.x;
  const float* row = lstm_out + (size_t)rw * 1024;
  float s[9];
  #pragma unroll
  for (int l = 0; l < 9; l++) s[l] = 0.f;
  for (int e = j; e < 1024; e += 64) {
    float x = row[e];
    #pragma unroll
    for (int l = 0; l < 9; l++) s[l] += x * out_w[l * 1024 + e];
  }
  #pragma unroll
  for (int l = 0; l < 9; l++) {
    #pragma unroll
    for (int off = 32; off > 0; off >>= 1) s[l] += __shfl_xor(s[l], off);
  }
  float v = NEGV;
  if (j < 9) {
    float r = (j==0)?s[0]:(j==1)?s[1]:(j==2)?s[2]:(j==3)?s[3]:(j==4)?s[4]:
              (j==5)?s[5]:(j==6)?s[6]:(j==7)?s[7]:s[8];
    v = r + out_b[j];
  }
  if (j < LPAD) lg[(size_t)rw * LPAD + j] = v;
}

// ---------------------------------------------------------------- CRF gold score
__global__ __launch_bounds__(64) void crf_gold_kernel(
    const float* __restrict__ lg, const int* __restrict__ labels,
    const int* __restrict__ lens, const float* __restrict__ trn, float* __restrict__ gold)
{
  int b = blockIdx.x, j = threadIdx.x;
  int len = lens[b];
  const int* lab = labels + b * SEQ;
  const float* l0 = lg + (size_t)b * SEQ * LPAD;
  float s = 0.f;
  for (int t = j; t < SEQ; t += 64) {
    if (t < len) {
      s += l0[t * LPAD + lab[t]];
      if (t >= 1) s += trn[lab[t] * LPAD + lab[t - 1]];
    }
  }
  #pragma unroll
  for (int off = 32; off > 0; off >>= 1) s += __shfl_xor(s, off);
  if (j == 0) {
    s += trn[lab[0] * LPAD + 9];
    s += trn[10 * LPAD + lab[len - 1]];
    gold[b] = s;
  }
}

// ---------------------------------------------------------------- CRF norm + final loglik
__global__ __launch_bounds__(64) void crf_norm_kernel(
    const float* __restrict__ lg, const int* __restrict__ lens,
    const float* __restrict__ trn, const float* __restrict__ gold, float* __restrict__ out_ll)
{
  int b = blockIdx.x, i = threadIdx.x;
  int len = lens[b];
  const float* l0 = lg + (size_t)b * SEQ * LPAD;
  bool act = (i < LPAD);
  float trow[LPAD];
  #pragma unroll
  for (int jj = 0; jj < LPAD; jj++) trow[jj] = act ? trn[i * LPAD + jj] : 0.f;
  float alpha = act ? (l0[i] + trow[9]) : -1e30f;

  for (int t = 1; t < SEQ; t++) {
    float vj[LPAD];
    #pragma unroll
    for (int jj = 0; jj < LPAD; jj++) vj[jj] = __shfl(alpha, jj) + trow[jj];
    float mx = vj[0];
    #pragma unroll
    for (int jj = 1; jj < LPAD; jj++) mx = fmaxf(mx, vj[jj]);
    float sum = 0.f;
    #pragma unroll
    for (int jj = 0; jj < LPAD; jj++) sum += expf(vj[jj] - mx);
    float lgv = act ? l0[t * LPAD + i] : 0.f;
    float nw = mx + logf(sum) + lgv;
    if (act && t < len) alpha = nw;
  }
  float vj[LPAD];
  #pragma unroll
  for (int jj = 0; jj < LPAD; jj++) vj[jj] = __shfl(alpha, jj) + trn[10 * LPAD + jj];
  float mx = vj[0];
  #pragma unroll
  for (int jj = 1; jj < LPAD; jj++) mx = fmaxf(mx, vj[jj]);
  float sum = 0.f;
  #pragma unroll
  for (int jj = 0; jj < LPAD; jj++) sum += expf(vj[jj] - mx);
  if (i == 0) out_ll[b] = gold[b] - (mx + logf(sum));
}

// ================================================================ launch
extern "C" void kernel_launch(void* const* d_in, const int* in_sizes, int n_in,
                              void* d_out, int out_size, void* d_ws, size_t ws_size,
                              hipStream_t stream)
{
  (void)in_sizes; (void)n_in; (void)out_size; (void)ws_size;
  const int*   token_ids = (const int*)d_in[0];
  const int*   char_ids  = (const int*)d_in[1];
  const int*   lens      = (const int*)d_in[2];
  const int*   labels    = (const int*)d_in[3];
  const float* word_embed= (const float*)d_in[4];
  const float* char_embed= (const float*)d_in[5];
  const float* w2 = (const float*)d_in[6];  const float* cb2 = (const float*)d_in[7];
  const float* w3 = (const float*)d_in[8];  const float* cb3 = (const float*)d_in[9];
  const float* w4 = (const float*)d_in[10]; const float* cb4 = (const float*)d_in[11];
  const float* w5 = (const float*)d_in[12]; const float* cb5 = (const float*)d_in[13];
  const float* ff_w = (const float*)d_in[14]; const float* ff_b = (const float*)d_in[15];
  const float* wgate_w = (const float*)d_in[16];
  const float* cgate_w = (const float*)d_in[17];
  const float* gate_w  = (const float*)d_in[18];
  const float* wih_f = (const float*)d_in[19]; const float* whh_f = (const float*)d_in[20];
  const float* b_f   = (const float*)d_in[21];
  const float* wih_b = (const float*)d_in[22]; const float* whh_b = (const float*)d_in[23];
  const float* b_b   = (const float*)d_in[24];
  const float* out_w = (const float*)d_in[25]; const float* out_b = (const float*)d_in[26];
  const float* trn   = (const float*)d_in[27];

  char* ws = (char*)d_ws;
  size_t off = 0;
  auto alloc = [&](size_t bytes) { void* p = ws + off; off += (bytes + 255) & ~(size_t)255; return p; };
  float* ch       = (float*)alloc((size_t)NWORD * 256 * 4);
  float* word_in  = (float*)alloc((size_t)NWORD * WDIM * 4);
  float* char_in  = (float*)alloc((size_t)NWORD * WDIM * 4);
  float* t1       = (float*)alloc((size_t)NWORD * WDIM * 4);
  float* gbuf     = (float*)alloc((size_t)NWORD * WDIM * 4);
  float* feats    = (float*)alloc((size_t)NWORD * WDIM * 4);
  unsigned short* xgf = (unsigned short*)alloc((size_t)NWORD * 2048 * 2);
  unsigned short* xgb = (unsigned short*)alloc((size_t)NWORD * 2048 * 2);
  float* lstm_o   = (float*)alloc((size_t)NWORD * 1024 * 4);
  unsigned short* hglob = (unsigned short*)alloc((size_t)2 * 2 * NB * HD * 2);
  float* gold     = (float*)alloc((size_t)NB * 4);
  unsigned* flags = (unsigned*)alloc(256);

  float* outp   = (float*)d_out;
  float* loglik = outp;
  float* logits = outp + NB;

  conv_kernel<<<NWORD, 256, 0, stream>>>(char_ids, char_embed, w2, cb2, w3, cb3, w4, cb4, w5, cb5, ch);
  gather_word_kernel<<<(NWORD * WDIM + 255) / 256, 256, 0, stream>>>(token_ids, word_embed, word_in);
  gemm_bt_kernel<<<32 * 3, 256, 0, stream>>>(ch, ff_w, ff_b, nullptr, char_in, nullptr, NWORD, 300, 256, 0, 3);
  gemm_bt_kernel<<<32 * 3, 256, 0, stream>>>(word_in, wgate_w, nullptr, nullptr, t1, nullptr, NWORD, 300, 300, 0, 3);
  gemm_bt_kernel<<<32 * 3, 256, 0, stream>>>(char_in, cgate_w, nullptr, t1, t1, nullptr, NWORD, 300, 300, 1, 3);
  gemm_bt_kernel<<<32 * 3, 256, 0, stream>>>(t1, gate_w, nullptr, nullptr, gbuf, nullptr, NWORD, 300, 300, 2, 3);
  feats_kernel<<<(NWORD * WDIM + 255) / 256, 256, 0, stream>>>(gbuf, word_in, char_in, feats, flags);
  gemm_bt_kernel<<<32 * 16, 256, 0, stream>>>(feats, wih_f, b_f, nullptr, nullptr, xgf, NWORD, 2048, 300, 0, 16);
  gemm_bt_kernel<<<32 * 16, 256, 0, stream>>>(feats, wih_b, b_b, nullptr, nullptr, xgb, NWORD, 2048, 300, 0, 16);
  {
    void* args[] = { (void*)&xgf, (void*)&xgb, (void*)&whh_f, (void*)&whh_b,
                     (void*)&lens, (void*)&lstm_o, (void*)&hglob, (void*)&flags };
    hipLaunchCooperativeKernel((void*)lstm_kernel, dim3(LSTM_BLOCKS), dim3(512), args, 0, stream);
  }
  logits_kernel<<<NWORD, 64, 0, stream>>>(lstm_o, out_w, out_b, logits);
  crf_gold_kernel<<<NB, 64, 0, stream>>>(logits, labels, lens, trn, gold);
  crf_norm_kernel<<<NB, 64, 0, stream>>>(logits, lens, trn, gold, loglik);
}